// Round 8
// baseline (482.255 us; speedup 1.0000x reference)
//
#include <hip/hip_runtime.h>
#include <hip/hip_fp16.h>

// NCN: 4x (MFMA-f16 GEMM + scan). In-place half-row ping-pong in d_out:
//   modules 0-2: row r (4KB) = [ y f16 (2KB) | mix f16 (2KB) ]
//   module  3  : gemm writes mix f32 full row; scan_f overwrites slot-wise.
// gemm blocks cover ALL heads of a contiguous row range (contiguous HBM/L3
// streams), staged via XOR-swizzled LDS. MFMA f16 1-pass (W quant 2^-12).
// scan: y[t]=tanh(0.5*cache+0.5*mix[t]), cache=y[t-8]; final caches -> ya
// staging region (= next module's cache init; last module = real ya output).

typedef _Float16 half8 __attribute__((ext_vector_type(8)));
typedef float f32x4  __attribute__((ext_vector_type(4)));
typedef unsigned int uint4v __attribute__((ext_vector_type(4)));

constexpr int B  = 8;
constexpr int T  = 4096;
constexpr int D  = 1024;
constexpr int H  = 16;
constexpr int DH = 64;
constexpr int NC = 8;
constexpr int NM = 4;

// MODE 0: input = x f32 (d_in, full rows), output = mix f16 (2nd half), 16 rows/blk
// MODE 1: input = y f16 (1st half),        output = mix f16 (2nd half), 32 rows/blk
// MODE 2: input = y f16 (1st half),        output = mix f32 (full row), 32 rows/blk
template <int MODE>
__global__ __launch_bounds__(512, 4)
void gemm_mix(const float* __restrict__ inF, float* __restrict__ buf,
              const float* __restrict__ w) {
  constexpr int ROWS = (MODE == 0) ? 16 : 32;
  constexpr int RB   = (MODE == 0) ? 4096 : 2048;   // staged bytes per row
  __shared__ alignas(16) unsigned char xs[65536];

  const int tid = threadIdx.x, lane = tid & 63, wv = tid >> 6;
  const int nrb  = T / ROWS;
  const int rblk = blockIdx.x % nrb;
  const int b    = blockIdx.x / nrb;
  const size_t row0 = (size_t)b * T + (size_t)rblk * ROWS;
  const int lr = lane & 15, lg = lane >> 4;

  // ---- stage input rows (fully coalesced), 16B granules XOR-swizzled
  const unsigned char* src = (MODE == 0)
      ? (const unsigned char*)inF + row0 * 4096
      : (const unsigned char*)buf + row0 * 4096;   // f16 y = first 2KB of row
#pragma unroll
  for (int p = 0; p < 8; ++p) {                    // 8*512*16B = 64KB
    const int gid = p * 512 + tid;
    const int row = gid / (RB / 16);
    const int col = gid % (RB / 16);
    const uint4v v = *(const uint4v*)(src + (size_t)row * 4096 + col * 16);
    *(uint4v*)(xs + row * RB + ((col * 16) ^ ((row & 7) << 4))) = v;
  }
  __syncthreads();

  // ---- wave handles 2 heads x all ROWS
#pragma unroll
  for (int hh = 0; hh < 2; ++hh) {
    const int h = wv * 2 + hh;
    const float* wh = w + (size_t)h * DH * DH;     // W[d][e] row-major

    // W fragments (A-operand), f16 1-pass: Wf[it][kt][e] = W[kt*32+lg*8+e][it*16+lr]
    half8 Wf[4][2];
#pragma unroll
    for (int it = 0; it < 4; ++it)
#pragma unroll
      for (int kt = 0; kt < 2; ++kt)
#pragma unroll
        for (int e = 0; e < 8; ++e)
          Wf[it][kt][e] =
              (_Float16)wh[(size_t)(kt * 32 + lg * 8 + e) * DH + it * 16 + lr];

    // X fragments (B-operand) from LDS
    constexpr int NJ = ROWS / 16;
    half8 Xf[NJ][2];
#pragma unroll
    for (int jt = 0; jt < NJ; ++jt)
#pragma unroll
      for (int kt = 0; kt < 2; ++kt) {
        const int row = jt * 16 + lr;
        if constexpr (MODE == 0) {                 // f32 in LDS -> cvt
          const int bir0 = h * 256 + kt * 128 + lg * 32;
          const f32x4 a0 = *(const f32x4*)(xs + row * RB + (bir0 ^ ((row & 7) << 4)));
          const f32x4 a1 = *(const f32x4*)(xs + row * RB + ((bir0 + 16) ^ ((row & 7) << 4)));
          half8 xv;
#pragma unroll
          for (int e = 0; e < 4; ++e) { xv[e] = (_Float16)a0[e]; xv[4 + e] = (_Float16)a1[e]; }
          Xf[jt][kt] = xv;
        } else {                                   // f16 in LDS, direct
          const int bir = h * 128 + kt * 64 + lg * 16;
          Xf[jt][kt] = *(const half8*)(xs + row * RB + (bir ^ ((row & 7) << 4)));
        }
      }

    // MFMA: C'[i=e][j=t], one pass
    f32x4 acc[4][NJ];
#pragma unroll
    for (int it = 0; it < 4; ++it)
#pragma unroll
      for (int jt = 0; jt < NJ; ++jt) acc[it][jt] = (f32x4){0.f, 0.f, 0.f, 0.f};
#pragma unroll
    for (int kt = 0; kt < 2; ++kt)
#pragma unroll
      for (int it = 0; it < 4; ++it)
#pragma unroll
        for (int jt = 0; jt < NJ; ++jt)
          acc[it][jt] = __builtin_amdgcn_mfma_f32_16x16x32_f16(
              Wf[it][kt], Xf[jt][kt], acc[it][jt], 0, 0, 0);

    // store: lane holds e = it*16+lg*4+{0..3}, t-row = jt*16+lr
#pragma unroll
    for (int it = 0; it < 4; ++it)
#pragma unroll
      for (int jt = 0; jt < NJ; ++jt) {
        const size_t row = row0 + jt * 16 + lr;
        const f32x4 a = acc[it][jt];
        if constexpr (MODE == 2) {
          *(f32x4*)&buf[row * D + h * DH + it * 16 + lg * 4] = a;
        } else {
          const __half2 p0 = __floats2half2_rn(a.x, a.y);
          const __half2 p1 = __floats2half2_rn(a.z, a.w);
          uint2 uv;
          uv.x = __builtin_bit_cast(unsigned, p0);
          uv.y = __builtin_bit_cast(unsigned, p1);
          *(uint2*)((unsigned char*)buf + row * 4096 + 2048 +
                    2 * (h * DH + it * 16 + lg * 4)) = uv;
        }
      }
  }
}

// ---- scan modules 0-2: read mix f16 (2nd half), write y f16 (1st half) ----
__global__ __launch_bounds__(256)
void scan_h(float* __restrict__ buf, const float* __restrict__ cinit,
            float* __restrict__ yaOut) {
  const int tid = threadIdx.x, bx = blockIdx.x;
  const int b = bx >> 5, c = (bx >> 2) & 7, d = (bx & 3) * 256 + tid;

  float cache = cinit[((size_t)b * NC + c) * D + d];
  __half* mp = (__half*)buf;                      // 2048 halves per row
  const size_t base = ((size_t)b * T + c) * 2048;
  constexpr size_t ST = (size_t)NC * 2048;        // 8 rows

  float cur[8], nxt[8];
#pragma unroll
  for (int j = 0; j < 8; ++j)
    cur[j] = __half2float(mp[base + 1024 + d + (size_t)j * ST]);

  for (int k = 0; k < 64; ++k) {
    if (k < 63) {
#pragma unroll
      for (int j = 0; j < 8; ++j)
        nxt[j] = __half2float(mp[base + 1024 + d + (size_t)((k + 1) * 8 + j) * ST]);
    }
#pragma unroll
    for (int j = 0; j < 8; ++j) {
      const float z = cache + cur[j];             // tanh(0.5(cache+mix))
      const float e = __expf(z);
      const float y = 1.0f - 2.0f * __builtin_amdgcn_rcpf(e + 1.0f);
      mp[base + d + (size_t)(k * 8 + j) * ST] = __float2half_rn(y);
      cache = y;
    }
#pragma unroll
    for (int j = 0; j < 8; ++j) cur[j] = nxt[j];
  }
  yaOut[((size_t)b * NC + c) * D + d] = cache;
}

// ---- scan module 3: mix f32 slot-wise in place -> y f32 (final output) ----
__global__ __launch_bounds__(256)
void scan_f(float* __restrict__ buf, const float* __restrict__ cinit,
            float* __restrict__ yaOut) {
  const int tid = threadIdx.x, bx = blockIdx.x;
  const int b = bx >> 5, c = (bx >> 2) & 7, d = (bx & 3) * 256 + tid;

  float cache = cinit[((size_t)b * NC + c) * D + d];
  float* p = buf + ((size_t)b * T + c) * D + d;
  constexpr size_t ST = (size_t)NC * D;

  float cur[8], nxt[8];
#pragma unroll
  for (int j = 0; j < 8; ++j) cur[j] = p[(size_t)j * ST];

  for (int k = 0; k < 64; ++k) {
    if (k < 63) {
#pragma unroll
      for (int j = 0; j < 8; ++j) nxt[j] = p[(size_t)((k + 1) * 8 + j) * ST];
    }
#pragma unroll
    for (int j = 0; j < 8; ++j) {
      const float z = cache + cur[j];
      const float e = __expf(z);
      const float y = 1.0f - 2.0f * __builtin_amdgcn_rcpf(e + 1.0f);
      p[(size_t)(k * 8 + j) * ST] = y;
      cache = y;
    }
#pragma unroll
    for (int j = 0; j < 8; ++j) cur[j] = nxt[j];
  }
  yaOut[((size_t)b * NC + c) * D + d] = cache;
}

extern "C" void kernel_launch(void* const* d_in, const int* in_sizes, int n_in,
                              void* d_out, int out_size, void* d_ws, size_t ws_size,
                              hipStream_t stream) {
  (void)in_sizes; (void)n_in; (void)d_ws; (void)ws_size; (void)out_size;
  const float* x  = (const float*)d_in[0];
  const float* xa = (const float*)d_in[1];
  const float* w  = (const float*)d_in[2];
  float* buf     = (float*)d_out;                        // [B,T,D] in-place
  float* yaStage = (float*)d_out + (size_t)B * T * D;    // [B,NC,D] ya region

  // module 0
  hipLaunchKernelGGL((gemm_mix<0>), dim3(B * (T / 16)), dim3(512), 0, stream,
                     x, buf, w + 0 * H * DH * DH);
  hipLaunchKernelGGL(scan_h, dim3(256), dim3(256), 0, stream, buf, xa, yaStage);
  // modules 1,2
  for (int m = 1; m <= 2; ++m) {
    hipLaunchKernelGGL((gemm_mix<1>), dim3(B * (T / 32)), dim3(512), 0, stream,
                       nullptr, buf, w + (size_t)m * H * DH * DH);
    hipLaunchKernelGGL(scan_h, dim3(256), dim3(256), 0, stream, buf, yaStage,
                       yaStage);
  }
  // module 3
  hipLaunchKernelGGL((gemm_mix<2>), dim3(B * (T / 32)), dim3(512), 0, stream,
                     nullptr, buf, w + (size_t)3 * H * DH * DH);
  hipLaunchKernelGGL(scan_f, dim3(256), dim3(256), 0, stream, buf, yaStage,
                     yaStage);
}

// Round 9
// 373.118 us; speedup vs baseline: 1.2925x; 1.2925x over previous
//
#include <hip/hip_runtime.h>
#include <hip/hip_fp16.h>

// NCN: 4x (MFMA-f16 GEMM + scan) + final f16->f32 expand. In-place half-row
// ping-pong in d_out rows (4KB): [ y f16 (2KB) | mix f16 (2KB) ].
// ALL global accesses are consecutive-lane contiguous runs; all scatter is in
// XOR-swizzled LDS. W fragments pre-swizzled into d_ws by prep_w (fallback:
// in-kernel gather if ws too small).
// gemm: mix[t, h*64+e] = sum_d in[t, h*64+d] * W[m,h,d,e]  (MFMA f16 1-pass)
// scan: y[t] = tanh(0.5*cache + 0.5*mix[t]), cache = y[t-8] per (b,c,d) chain.

typedef _Float16 f16;
typedef _Float16 half8 __attribute__((ext_vector_type(8)));
typedef _Float16 half4v __attribute__((ext_vector_type(4)));
typedef float f32x4 __attribute__((ext_vector_type(4)));
typedef unsigned int uint4v __attribute__((ext_vector_type(4)));

constexpr int B  = 8;
constexpr int T  = 4096;
constexpr int D  = 1024;
constexpr int H  = 16;
constexpr int DH = 64;
constexpr int NC = 8;
constexpr int ROWS = 16;                 // rows per gemm block
constexpr size_t WIMG_BYTES = (size_t)4 * H * 8 * 64 * sizeof(half8); // 512KB

__device__ __forceinline__ int swz(int row, int byteoff) {
  return byteoff ^ ((row & 7) << 4);     // 16B-granule XOR swizzle per row
}

// ---- W fragment image: img[((m*16+h)*8 + it*2+kt)*64 + lane] = half8,
//      element j = W[m,h, d=kt*32+(lane>>4)*8+j, e=it*16+(lane&15)]
__global__ __launch_bounds__(256)
void prep_w(const float* __restrict__ w, half8* __restrict__ img) {
  const int gid  = blockIdx.x * 256 + threadIdx.x;  // [0, 32768)
  const int lane = gid & 63;
  const int f    = (gid >> 6) & 7;
  const int h    = (gid >> 9) & 15;
  const int m    = gid >> 13;
  const int it = f >> 1, kt = f & 1;
  const int lr = lane & 15, lg = lane >> 4;
  const float* wh = w + (size_t)(m * H + h) * DH * DH;
  half8 v;
#pragma unroll
  for (int j = 0; j < 8; ++j)
    v[j] = (f16)wh[(size_t)(kt * 32 + lg * 8 + j) * DH + it * 16 + lr];
  img[gid] = v;
}

// MODE 0: input = x f32 full rows; MODE 1: input = y f16 (first 2KB of row).
// Output: mix f16 into second 2KB of row. grid = B*T/ROWS, block 512 (8 waves).
template <int MODE, bool WIMG>
__global__ __launch_bounds__(512, 2)
void gemm_mix(const float* __restrict__ xin, float* __restrict__ buf,
              const float* __restrict__ wm, const half8* __restrict__ wimg) {
  __shared__ __align__(16) unsigned char XS[ROWS * 2048];  // f16, swizzled
  __shared__ __align__(16) unsigned char MS[ROWS * 2048];  // f16 mix, swizzled

  const int tid = threadIdx.x, lane = tid & 63, wv = tid >> 6;
  const int rblk = blockIdx.x & 255;               // T/ROWS = 256 per b
  const int b    = blockIdx.x >> 8;
  const size_t row0 = (size_t)b * T + (size_t)rblk * ROWS;
  const int lr = lane & 15, lg = lane >> 4;
  unsigned char* const bufb = (unsigned char*)buf;

  // ---- stage input rows -> XS (contiguous global reads)
  if constexpr (MODE == 0) {
    const unsigned char* src = (const unsigned char*)xin + row0 * 4096;
#pragma unroll
    for (int p = 0; p < 8; ++p) {                  // 16 rows * 256 f32x4 chunks
      const int gid = p * 512 + tid;
      const int row = gid >> 8, c4 = gid & 255;
      const f32x4 v = *(const f32x4*)(src + (size_t)row * 4096 + c4 * 16);
      half4v hv;
#pragma unroll
      for (int e = 0; e < 4; ++e) hv[e] = (f16)v[e];
      *(half4v*)(XS + row * 2048 + swz(row, c4 * 8)) = hv;
    }
  } else {
    const unsigned char* src = bufb + row0 * 4096; // f16 y = first 2KB of row
#pragma unroll
    for (int p = 0; p < 4; ++p) {                  // 16 rows * 128 granules
      const int gid = p * 512 + tid;
      const int row = gid >> 7, c16 = gid & 127;
      const uint4v v = *(const uint4v*)(src + (size_t)row * 4096 + c16 * 16);
      *(uint4v*)(XS + row * 2048 + swz(row, c16 * 16)) = v;
    }
  }
  __syncthreads();

  // ---- per wave: 2 heads; per head: 4 it-tiles x 2 kt, 8 MFMAs
#pragma unroll
  for (int hh = 0; hh < 2; ++hh) {
    const int h = wv * 2 + hh;

    half8 Wf[4][2];
    if constexpr (WIMG) {
#pragma unroll
      for (int it = 0; it < 4; ++it)
#pragma unroll
        for (int kt = 0; kt < 2; ++kt)
          Wf[it][kt] = wimg[(size_t)(h * 8 + it * 2 + kt) * 64 + lane];
    } else {
      const float* wh = wm + (size_t)h * DH * DH;
#pragma unroll
      for (int it = 0; it < 4; ++it)
#pragma unroll
        for (int kt = 0; kt < 2; ++kt)
#pragma unroll
          for (int j = 0; j < 8; ++j)
            Wf[it][kt][j] =
                (f16)wh[(size_t)(kt * 32 + lg * 8 + j) * DH + it * 16 + lr];
    }

    // X A-frags from LDS: row = lr (t), k-slot d = kt*32 + lg*8 + e
    half8 Xf[2];
#pragma unroll
    for (int kt = 0; kt < 2; ++kt)
      Xf[kt] = *(const half8*)(XS + lr * 2048 +
                               swz(lr, h * 128 + kt * 64 + lg * 16));

    f32x4 acc[4];
#pragma unroll
    for (int it = 0; it < 4; ++it) acc[it] = (f32x4){0.f, 0.f, 0.f, 0.f};
#pragma unroll
    for (int kt = 0; kt < 2; ++kt)
#pragma unroll
      for (int it = 0; it < 4; ++it)
        acc[it] = __builtin_amdgcn_mfma_f32_16x16x32_f16(Xf[kt], Wf[it][kt],
                                                         acc[it], 0, 0, 0);

    // epilogue scatter into MS (LDS): C col = lr (e), row = lg*4 + j (t)
#pragma unroll
    for (int it = 0; it < 4; ++it)
#pragma unroll
      for (int j = 0; j < 4; ++j) {
        const int row = lg * 4 + j;
        const int col = h * 64 + it * 16 + lr;     // half index in row
        *(f16*)(MS + row * 2048 + swz(row, col * 2)) = (f16)acc[it][j];
      }
  }
  __syncthreads();

  // ---- out-stage: mix f16 -> second 2KB of each row (contiguous writes)
#pragma unroll
  for (int p = 0; p < 4; ++p) {
    const int gid = p * 512 + tid;
    const int row = gid >> 7, c16 = gid & 127;
    const uint4v v = *(const uint4v*)(MS + row * 2048 + swz(row, c16 * 16));
    *(uint4v*)(bufb + (row0 + row) * 4096 + 2048 + c16 * 16) = v;
  }
}

// ---- scan: read mix f16 (2nd half), write y f16 (1st half); cache f32 ----
__global__ __launch_bounds__(256)
void scan_h(float* __restrict__ buf, const float* __restrict__ cinit,
            float* __restrict__ yaOut) {
  const int tid = threadIdx.x, bx = blockIdx.x;
  const int b = bx >> 5, c = (bx >> 2) & 7, d = (bx & 3) * 256 + tid;

  float cache = cinit[((size_t)b * NC + c) * D + d];
  __half* mp = (__half*)buf;                      // 2048 halves per row
  const size_t base = ((size_t)b * T + c) * 2048;
  constexpr size_t ST = (size_t)NC * 2048;        // 8 rows

  float cur[8], nxt[8];
#pragma unroll
  for (int j = 0; j < 8; ++j)
    cur[j] = __half2float(mp[base + 1024 + d + (size_t)j * ST]);

  for (int k = 0; k < 64; ++k) {
    if (k < 63) {
#pragma unroll
      for (int j = 0; j < 8; ++j)
        nxt[j] = __half2float(mp[base + 1024 + d + (size_t)((k + 1) * 8 + j) * ST]);
    }
#pragma unroll
    for (int j = 0; j < 8; ++j) {
      const float z = cache + cur[j];             // tanh(0.5(cache+mix))
      const float e = __expf(z);
      const float y = 1.0f - 2.0f * __builtin_amdgcn_rcpf(e + 1.0f);
      mp[base + d + (size_t)(k * 8 + j) * ST] = __float2half_rn(y);
      cache = y;
    }
#pragma unroll
    for (int j = 0; j < 8; ++j) cur[j] = nxt[j];
  }
  yaOut[((size_t)b * NC + c) * D + d] = cache;
}

// ---- expand: y f16 (first 2KB) -> full f32 rows, in place, 4 rows/block ----
__global__ __launch_bounds__(256)
void expand(float* __restrict__ buf) {
  __shared__ __align__(16) f16 rs[4 * 1024];
  const int tid = threadIdx.x;
  unsigned char* const base = (unsigned char*)buf + (size_t)blockIdx.x * 4 * 4096;
#pragma unroll
  for (int p = 0; p < 2; ++p) {                    // 4 rows * 2KB = 8KB in
    const int gid = p * 256 + tid;
    const int row = gid >> 7, c16 = gid & 127;
    *(uint4v*)((unsigned char*)rs + row * 2048 + c16 * 16) =
        *(const uint4v*)(base + (size_t)row * 4096 + c16 * 16);
  }
  __syncthreads();
#pragma unroll
  for (int p = 0; p < 4; ++p) {                    // 4 rows * 4KB = 16KB out
    const int gid = p * 256 + tid;
    const int row = gid >> 8, c4 = gid & 255;
    const half4v hv = *(const half4v*)((unsigned char*)rs + row * 2048 + c4 * 8);
    f32x4 v;
#pragma unroll
    for (int e = 0; e < 4; ++e) v[e] = (float)hv[e];
    *(f32x4*)(base + (size_t)row * 4096 + c4 * 16) = v;
  }
}

extern "C" void kernel_launch(void* const* d_in, const int* in_sizes, int n_in,
                              void* d_out, int out_size, void* d_ws, size_t ws_size,
                              hipStream_t stream) {
  (void)in_sizes; (void)n_in; (void)out_size;
  const float* x  = (const float*)d_in[0];
  const float* xa = (const float*)d_in[1];
  const float* w  = (const float*)d_in[2];
  float* buf     = (float*)d_out;                        // [B,T,D] in-place
  float* yaStage = (float*)d_out + (size_t)B * T * D;    // [B,NC,D] ya region

  const bool useimg = (ws_size >= WIMG_BYTES) && (d_ws != nullptr);
  half8* img = (half8*)d_ws;
  if (useimg)
    hipLaunchKernelGGL(prep_w, dim3(128), dim3(256), 0, stream, w, img);

  const dim3 gg(B * (T / ROWS)), gb(512);
  for (int m = 0; m < 4; ++m) {
    const float* wm = w + (size_t)m * H * DH * DH;
    const half8* wi = img + (size_t)m * H * 8 * 64;
    if (m == 0) {
      if (useimg)
        hipLaunchKernelGGL((gemm_mix<0, true>), gg, gb, 0, stream, x, buf, wm, wi);
      else
        hipLaunchKernelGGL((gemm_mix<0, false>), gg, gb, 0, stream, x, buf, wm, wi);
    } else {
      if (useimg)
        hipLaunchKernelGGL((gemm_mix<1, true>), gg, gb, 0, stream, buf, buf, wm, wi);
      else
        hipLaunchKernelGGL((gemm_mix<1, false>), gg, gb, 0, stream, buf, buf, wm, wi);
    }
    hipLaunchKernelGGL(scan_h, dim3(256), dim3(256), 0, stream, buf,
                       (m == 0) ? xa : yaStage, yaStage);
  }
  hipLaunchKernelGGL(expand, dim3(B * T / 4), dim3(256), 0, stream, buf);
}

// Round 10
// 237.224 us; speedup vs baseline: 2.0329x; 1.5729x over previous
//
#include <hip/hip_runtime.h>
#include <hip/hip_fp16.h>

// NCN fully fused per (b,h): 128 independent [T=4096 x 64] subproblems.
// One persistent block per (b,h) runs all 4 modules; mix lives ONLY in LDS;
// y handoff between modules = f16 in first 2KB of each 4KB d_out row
// (in-place, 128B-line coalesced); caches stay in registers across modules.
// Final expand kernel converts y f16 -> f32 full rows (R8-validated).
// MFMA f16 1-pass, fragment mappings identical to validated R8 kernel.

typedef _Float16 f16;
typedef _Float16 half8 __attribute__((ext_vector_type(8)));
typedef float f32x4 __attribute__((ext_vector_type(4)));
typedef unsigned uint4v __attribute__((ext_vector_type(4)));

constexpr int B = 8, T = 4096, D = 1024, H = 16, DH = 64, NC = 8, NM = 4;
constexpr int CH = 256;              // rows per chunk
constexpr int NCHUNK = T / CH;       // 16

__global__ __launch_bounds__(512, 1)
void ncn_main(const float* __restrict__ x, const float* __restrict__ xa,
              const float* __restrict__ w, float* __restrict__ out) {
  __shared__ __align__(16) unsigned char YL[CH * 128];      // y chunk f16, swz
  __shared__ __align__(16) unsigned char MX[DH * CH * 2];   // mix [e][t] f16, swz

  const int tid = threadIdx.x, lane = tid & 63, wv = tid >> 6;
  const int h = blockIdx.x & 15, b = blockIdx.x >> 4;
  const int lr = lane & 15, lg = lane >> 4;
  const int c = wv, d = lane;        // chain identity (wave = c, lane = d)

  unsigned char* const rows = (unsigned char*)out + (size_t)b * T * 4096;
  const unsigned char* const xrows = (const unsigned char*)x + (size_t)b * T * 4096;

  float cache = xa[((size_t)b * NC + c) * D + h * DH + d];

  // stage mappings
  const int srow = tid >> 3, scol = (tid & 7) * 16;    // f16 path: rows srow+64i
  const int frow = tid >> 4, fcol = (tid & 15) * 16;   // f32 path: rows frow+32i

  uint4v pf[8];

  for (int m = 0; m < NM; ++m) {
    // W fragments (B-operand), per validated R8 mapping:
    // Wf[it][kt][j] = W[m,h, d=kt*32+lg*8+j, e=it*16+lr]
    const float* wh = w + ((size_t)m * H + h) * DH * DH;
    half8 Wf[4][2];
#pragma unroll
    for (int it = 0; it < 4; ++it)
#pragma unroll
      for (int kt = 0; kt < 2; ++kt)
#pragma unroll
        for (int j = 0; j < 8; ++j)
          Wf[it][kt][j] = (f16)wh[(size_t)(kt * 32 + lg * 8 + j) * DH + it * 16 + lr];

    // module boundary: all waves' previous-module y stores must be complete
    asm volatile("s_waitcnt vmcnt(0)" ::: "memory");
    __syncthreads();

    // prefetch chunk 0
    if (m == 0) {
#pragma unroll
      for (int i = 0; i < 8; ++i)
        pf[i] = *(const uint4v*)(xrows + (size_t)(i * 32 + frow) * 4096 + h * 256 + fcol);
    } else {
#pragma unroll
      for (int i = 0; i < 4; ++i)
        pf[i] = *(const uint4v*)(rows + (size_t)(i * 64 + srow) * 4096 + h * 128 + scol);
    }

    for (int ch = 0; ch < NCHUNK; ++ch) {
      const int t0 = ch * CH;

      // ---- stage prefetched y/x into YL (compiler inserts counted vmcnt)
      if (m == 0) {
#pragma unroll
        for (int i = 0; i < 8; ++i) {
          const int r = i * 32 + frow;
          const f32x4 v = __builtin_bit_cast(f32x4, pf[i]);
          const __half2 a = __floats2half2_rn(v.x, v.y);
          const __half2 bq = __floats2half2_rn(v.z, v.w);
          uint2 pk;
          pk.x = __builtin_bit_cast(unsigned, a);
          pk.y = __builtin_bit_cast(unsigned, bq);
          *(uint2*)(YL + r * 128 + ((fcol >> 1) ^ ((r & 7) << 4))) = pk;
        }
      } else {
#pragma unroll
        for (int i = 0; i < 4; ++i) {
          const int r = i * 64 + srow;
          *(uint4v*)(YL + r * 128 + (scol ^ ((r & 7) << 4))) = pf[i];
        }
      }
      __syncthreads();

      // ---- issue next-chunk loads (hide under gemm + scan)
      if (ch + 1 < NCHUNK) {
        const int t1 = t0 + CH;
        if (m == 0) {
#pragma unroll
          for (int i = 0; i < 8; ++i)
            pf[i] = *(const uint4v*)(xrows + (size_t)(t1 + i * 32 + frow) * 4096 +
                                     h * 256 + fcol);
        } else {
#pragma unroll
          for (int i = 0; i < 4; ++i)
            pf[i] = *(const uint4v*)(rows + (size_t)(t1 + i * 64 + srow) * 4096 +
                                     h * 128 + scol);
        }
      }

      // ---- gemm phase: 2 t-tiles of 16 rows per wave
#pragma unroll
      for (int q = 0; q < 2; ++q) {
        const int tt = wv * 2 + q;
        const int r = tt * 16 + lr;
        half8 Xf[2];
#pragma unroll
        for (int kt = 0; kt < 2; ++kt)
          Xf[kt] = *(const half8*)(YL + r * 128 +
                                   ((kt * 64 + lg * 16) ^ ((r & 7) << 4)));
        f32x4 acc[4];
#pragma unroll
        for (int it = 0; it < 4; ++it) acc[it] = (f32x4){0.f, 0.f, 0.f, 0.f};
#pragma unroll
        for (int kt = 0; kt < 2; ++kt)
#pragma unroll
          for (int it = 0; it < 4; ++it)
            acc[it] = __builtin_amdgcn_mfma_f32_16x16x32_f16(Xf[kt], Wf[it][kt],
                                                             acc[it], 0, 0, 0);
        // C: per lane e = it*16+lr fixed, t = tt*16 + lg*4 + j (4 consecutive)
        // -> one b64 write per it into MX[e][t] (XOR-swizzled)
#pragma unroll
        for (int it = 0; it < 4; ++it) {
          const __half2 p0 = __floats2half2_rn(acc[it].x, acc[it].y);
          const __half2 p1 = __floats2half2_rn(acc[it].z, acc[it].w);
          uint2 pk;
          pk.x = __builtin_bit_cast(unsigned, p0);
          pk.y = __builtin_bit_cast(unsigned, p1);
          const int e = it * 16 + lr;
          *(uint2*)(MX + e * (CH * 2) +
                    (((tt * 16 + lg * 4) * 2) ^ ((e & 15) << 3))) = pk;
        }
      }
      __syncthreads();

      // ---- scan phase: 32 steps per chain; mix from LDS, y f16 -> global
#pragma unroll
      for (int k = 0; k < CH / NC; ++k) {
        const int tl = k * 8 + c;
        const float mixv =
            (float)*(const f16*)(MX + d * (CH * 2) + ((tl * 2) ^ ((d & 15) << 3)));
        const float z = cache + mixv;                    // tanh(0.5(cache+mix))
        const float e = __expf(z);
        cache = 1.0f - 2.0f * __builtin_amdgcn_rcpf(e + 1.0f);
        *(__half*)(rows + (size_t)(t0 + tl) * 4096 + h * 128 + 2 * d) =
            __float2half_rn(cache);
      }
      // no barrier needed here: next stage_write touches only YL (gemm done),
      // next gemm's MX writes are fenced by the loop-top __syncthreads.
    }
  }

  // final caches -> ya output (exclusive cells, no race)
  float* ya = out + (size_t)B * T * D;
  ya[((size_t)b * NC + c) * D + h * DH + d] = cache;
}

// ---- expand: y f16 (first 2KB of row) -> full f32 rows, in place (R8) ----
__global__ __launch_bounds__(256)
void expand(float* __restrict__ buf) {
  __shared__ __align__(16) f16 rs[4 * 1024];
  const int tid = threadIdx.x;
  unsigned char* const base = (unsigned char*)buf + (size_t)blockIdx.x * 4 * 4096;
#pragma unroll
  for (int p = 0; p < 2; ++p) {
    const int gid = p * 256 + tid;
    const int row = gid >> 7, c16 = gid & 127;
    *(uint4v*)((unsigned char*)rs + row * 2048 + c16 * 16) =
        *(const uint4v*)(base + (size_t)row * 4096 + c16 * 16);
  }
  __syncthreads();
#pragma unroll
  for (int p = 0; p < 4; ++p) {
    const int gid = p * 256 + tid;
    const int row = gid >> 8, c4 = gid & 255;
    const half8* hp = (const half8*)rs;  // silence unused-type warnings
    (void)hp;
    typedef _Float16 half4v __attribute__((ext_vector_type(4)));
    const half4v hv = *(const half4v*)((unsigned char*)rs + row * 2048 + c4 * 8);
    f32x4 v;
#pragma unroll
    for (int e = 0; e < 4; ++e) v[e] = (float)hv[e];
    *(f32x4*)(base + (size_t)row * 4096 + c4 * 16) = v;
  }
}

extern "C" void kernel_launch(void* const* d_in, const int* in_sizes, int n_in,
                              void* d_out, int out_size, void* d_ws, size_t ws_size,
                              hipStream_t stream) {
  (void)in_sizes; (void)n_in; (void)d_ws; (void)ws_size; (void)out_size;
  const float* x  = (const float*)d_in[0];
  const float* xa = (const float*)d_in[1];
  const float* w  = (const float*)d_in[2];
  float* out = (float*)d_out;

  hipLaunchKernelGGL(ncn_main, dim3(B * H), dim3(512), 0, stream, x, xa, w, out);
  hipLaunchKernelGGL(expand, dim3(B * T / 4), dim3(256), 0, stream, out);
}

// Round 12
// 165.267 us; speedup vs baseline: 2.9180x; 1.4354x over previous
//
#include <hip/hip_runtime.h>
#include <hip/hip_fp16.h>

// NCN fused per (b,h,chalf): 256 blocks x 256 thr (full machine). Block =
// 4 waves = 4 c-chains (c = chalf*4 + wv), 64 lanes = d. All 4 modules in one
// kernel; mix only in LDS; y handoff f16 in first 2KB of each 4KB d_out row;
// caches in registers across modules. MX transposed [e][c'][k] so each scan
// chain batch-loads its 32 mix values (4x ds_read_b128); serial loop is pure
// VALU. expand converts y f16 -> f32. MFMA mapping = R8/R9-validated:
// mfma(Xf, Wf); C: e = it*16+lr (col), t = tt*16+lg*4+j (row); k-slot =
// kt*32+lg*8+elem on both fragments.

typedef _Float16 f16;
typedef _Float16 half8 __attribute__((ext_vector_type(8)));
typedef _Float16 half4v __attribute__((ext_vector_type(4)));
typedef float f32x4 __attribute__((ext_vector_type(4)));
typedef unsigned uint4v __attribute__((ext_vector_type(4)));

constexpr int B = 8, T = 4096, D = 1024, H = 16, DH = 64, NC = 8, NM = 4;
constexpr int CH = 256;               // t-rows per chunk
constexpr int NCHUNK = T / CH;        // 16
constexpr int RPC = 128;              // staged rows per chunk (4 of 8 c's)

__global__ __launch_bounds__(256, 1)
void ncn_main(const float* __restrict__ x, const float* __restrict__ xa,
              const float* __restrict__ w, float* __restrict__ out) {
  __shared__ __align__(16) unsigned char YL[RPC * 128];   // y/x chunk f16, swz
  __shared__ __align__(16) unsigned char MX[64 * 256];    // [e][c'*64B + k*2], swz

  const int tid = threadIdx.x, lane = tid & 63, wv = tid >> 6;
  const int bx = blockIdx.x;                // 256 = (b:8)(h:16)(chalf:2)
  const int chalf = bx & 1, h = (bx >> 1) & 15, b = bx >> 5;
  const int cbase = chalf * 4;
  const int lr = lane & 15, lg = lane >> 4;
  const int c = cbase + wv;                 // this wave's chain slot
  const int d = lane;

  unsigned char* const rows = (unsigned char*)out + (size_t)b * T * 4096;
  const unsigned char* const xrows =
      (const unsigned char*)x + (size_t)b * T * 4096;

  float cache = xa[((size_t)b * NC + c) * D + h * DH + d];

  uint4v pf[8];

  for (int m = 0; m < NM; ++m) {
    // W fragments (validated): Wf[it][kt][j] = W[m,h, kt*32+lg*8+j, it*16+lr]
    const float* wh = w + ((size_t)m * H + h) * DH * DH;
    half8 Wf[4][2];
#pragma unroll
    for (int it = 0; it < 4; ++it)
#pragma unroll
      for (int kt = 0; kt < 2; ++kt)
#pragma unroll
        for (int j = 0; j < 8; ++j)
          Wf[it][kt][j] =
              (f16)wh[(size_t)(kt * 32 + lg * 8 + j) * DH + it * 16 + lr];

    // module boundary: all waves' previous-module y stores complete
    asm volatile("s_waitcnt vmcnt(0)" ::: "memory");
    __syncthreads();

    // ---- prefetch chunk 0; staged row lt <-> t = (lt>>2)*8 + cbase + (lt&3)
    if (m == 0) {
#pragma unroll
      for (int i = 0; i < 8; ++i) {
        const int gid = i * 256 + tid;          // [0,2048)
        const int c16 = gid & 15, lt = gid >> 4;
        const int t = ((lt >> 2) << 3) + cbase + (lt & 3);
        pf[i] = *(const uint4v*)(xrows + (size_t)t * 4096 + h * 256 + c16 * 16);
      }
    } else {
#pragma unroll
      for (int i = 0; i < 4; ++i) {
        const int gid = i * 256 + tid;          // [0,1024)
        const int c16 = gid & 7, lt = gid >> 3;
        const int t = ((lt >> 2) << 3) + cbase + (lt & 3);
        pf[i] = *(const uint4v*)(rows + (size_t)t * 4096 + h * 128 + c16 * 16);
      }
    }

    for (int ch = 0; ch < NCHUNK; ++ch) {
      const int t0 = ch * CH;

      // ---- stage prefetched rows into YL (swizzled)
      if (m == 0) {
#pragma unroll
        for (int i = 0; i < 8; ++i) {
          const int gid = i * 256 + tid;
          const int c16 = gid & 15, lt = gid >> 4;
          const f32x4 v = __builtin_bit_cast(f32x4, pf[i]);
          half4v hv;
#pragma unroll
          for (int e = 0; e < 4; ++e) hv[e] = (f16)v[e];
          *(half4v*)(YL + lt * 128 + ((c16 * 8) ^ ((lt & 7) << 4))) = hv;
        }
      } else {
#pragma unroll
        for (int i = 0; i < 4; ++i) {
          const int gid = i * 256 + tid;
          const int c16 = gid & 7, lt = gid >> 3;
          *(uint4v*)(YL + lt * 128 + ((c16 * 16) ^ ((lt & 7) << 4))) = pf[i];
        }
      }
      __syncthreads();

      // ---- issue next-chunk prefetch (hides under gemm + scan)
      if (ch + 1 < NCHUNK) {
        const int t1 = t0 + CH;
        if (m == 0) {
#pragma unroll
          for (int i = 0; i < 8; ++i) {
            const int gid = i * 256 + tid;
            const int c16 = gid & 15, lt = gid >> 4;
            const int t = t1 + ((lt >> 2) << 3) + cbase + (lt & 3);
            pf[i] = *(const uint4v*)(xrows + (size_t)t * 4096 + h * 256 + c16 * 16);
          }
        } else {
#pragma unroll
          for (int i = 0; i < 4; ++i) {
            const int gid = i * 256 + tid;
            const int c16 = gid & 7, lt = gid >> 3;
            const int t = t1 + ((lt >> 2) << 3) + cbase + (lt & 3);
            pf[i] = *(const uint4v*)(rows + (size_t)t * 4096 + h * 128 + c16 * 16);
          }
        }
      }

      // ---- gemm: wave does 2 t-tiles of 16 staged rows
#pragma unroll
      for (int q = 0; q < 2; ++q) {
        const int tt = wv * 2 + q;              // [0,8)
        const int r = tt * 16 + lr;             // staged row
        half8 Xf[2];
#pragma unroll
        for (int kt = 0; kt < 2; ++kt)
          Xf[kt] = *(const half8*)(YL + r * 128 +
                                   ((kt * 64 + lg * 16) ^ ((r & 7) << 4)));
        f32x4 acc[4];
#pragma unroll
        for (int it = 0; it < 4; ++it) acc[it] = (f32x4){0.f, 0.f, 0.f, 0.f};
#pragma unroll
        for (int kt = 0; kt < 2; ++kt)
#pragma unroll
          for (int it = 0; it < 4; ++it)
            acc[it] = __builtin_amdgcn_mfma_f32_16x16x32_f16(
                Xf[kt], Wf[it][kt], acc[it], 0, 0, 0);
        // scatter: staged row ltc = tt*16+lg*4+j -> c' = j, k = tt*4+lg
#pragma unroll
        for (int it = 0; it < 4; ++it) {
          const int e = it * 16 + lr;
#pragma unroll
          for (int j = 0; j < 4; ++j)
            *(f16*)(MX + e * 256 +
                    ((j * 64 + (tt * 4 + lg) * 2) ^ ((e & 7) << 4))) =
                (f16)acc[it][j];
        }
      }
      __syncthreads();

      // ---- scan: batch-load 32 mix values, then pure-VALU serial loop
      half8 mxr[4];
#pragma unroll
      for (int k16 = 0; k16 < 4; ++k16)
        mxr[k16] = *(const half8*)(MX + d * 256 +
                                   ((wv * 64 + k16 * 16) ^ ((d & 7) << 4)));
      unsigned char* sp = rows + (size_t)(t0 + c) * 4096 + h * 128 + 2 * d;
#pragma unroll
      for (int k = 0; k < 32; ++k) {
        const float mixv = (float)mxr[k >> 3][k & 7];
        const float z = cache + mixv;           // tanh(0.5(cache+mix))
        const float E = __expf(z);
        cache = 1.0f - 2.0f * __builtin_amdgcn_rcpf(E + 1.0f);
        *(__half*)sp = __float2half_rn(cache);
        sp += 8 * 4096;
      }
      // no barrier: next stage writes only YL (gemm finished at 2nd barrier);
      // next gemm's MX writes are fenced by the loop-top __syncthreads.
    }
  }

  // final caches -> ya output (exclusive cells)
  float* ya = out + (size_t)B * T * D;
  ya[((size_t)b * NC + c) * D + h * DH + d] = cache;
}

// ---- expand: y f16 (first 2KB of row) -> full f32 rows, in place ----
__global__ __launch_bounds__(256)
void expand(float* __restrict__ buf) {
  __shared__ __align__(16) f16 rs[4 * 1024];
  const int tid = threadIdx.x;
  unsigned char* const base = (unsigned char*)buf + (size_t)blockIdx.x * 4 * 4096;
#pragma unroll
  for (int p = 0; p < 2; ++p) {
    const int gid = p * 256 + tid;
    const int row = gid >> 7, c16 = gid & 127;
    *(uint4v*)((unsigned char*)rs + row * 2048 + c16 * 16) =
        *(const uint4v*)(base + (size_t)row * 4096 + c16 * 16);
  }
  __syncthreads();
#pragma unroll
  for (int p = 0; p < 4; ++p) {
    const int gid = p * 256 + tid;
    const int row = gid >> 8, c4 = gid & 255;
    const half4v hv = *(const half4v*)((unsigned char*)rs + row * 2048 + c4 * 8);
    f32x4 v;
#pragma unroll
    for (int e = 0; e < 4; ++e) v[e] = (float)hv[e];
    *(f32x4*)(base + (size_t)row * 4096 + c4 * 16) = v;
  }
}

extern "C" void kernel_launch(void* const* d_in, const int* in_sizes, int n_in,
                              void* d_out, int out_size, void* d_ws, size_t ws_size,
                              hipStream_t stream) {
  (void)in_sizes; (void)n_in; (void)d_ws; (void)ws_size; (void)out_size;
  const float* x  = (const float*)d_in[0];
  const float* xa = (const float*)d_in[1];
  const float* w  = (const float*)d_in[2];
  float* out = (float*)d_out;

  hipLaunchKernelGGL(ncn_main, dim3(256), dim3(256), 0, stream, x, xa, w, out);
  hipLaunchKernelGGL(expand, dim3(B * T / 4), dim3(256), 0, stream, out);
}